// Round 11
// baseline (1936.692 us; speedup 1.0000x reference)
//
#include <hip/hip_runtime.h>

#define BATCH 256
#define TSTEPS 4096
#define HID 136
#define ODIM 68
#define THREADS 64    // ONE wave: no barriers anywhere in the t-loop

typedef _Float16 h2 __attribute__((ext_vector_type(2)));

__device__ __forceinline__ float fast_tanh(float z) {
    float az = fabsf(z);
    float e = __expf(-2.0f * az);
    float r = (1.0f - e) * __builtin_amdgcn_rcpf(1.0f + e);
    return copysignf(r, z);
}

template <int CTRL>
__device__ __forceinline__ float dpp_add(float x) {
    int y = __builtin_amdgcn_update_dpp(0, __float_as_int(x), CTRL, 0xF, 0xF, false);
    return x + __int_as_float(y);
}
// butterfly over 8 consecutive lanes: all 8 end with the full sum (R6/R10-proven)
__device__ __forceinline__ float reduce8(float x) {
    x = dpp_add<0xB1>(x);    // quad_perm xor1
    x = dpp_add<0x4E>(x);    // quad_perm xor2
    x = dpp_add<0x141>(x);   // row_half_mirror
    return x;
}

__device__ __forceinline__ h2 bc_h2(unsigned int u) {
    union { unsigned int u; h2 h; } c; c.u = u; return c.h;
}

__global__ __launch_bounds__(THREADS)
void rnn_1w_dot2(const float* __restrict__ x,
                 const float* __restrict__ W_ih,
                 const float* __restrict__ W_hh,
                 const float* __restrict__ b_ih,
                 const float* __restrict__ b_hh,
                 const float* __restrict__ W_fc,
                 const float* __restrict__ b_fc,
                 float* __restrict__ out)
{
    __shared__ __align__(16) _Float16 hS[144];   // 288 B; [136..143] stay 0

    const int b    = blockIdx.x;
    const int lane = threadIdx.x;     // 0..63
    const int r0   = 2 * lane;        // owned rows
    const int r1   = 2 * lane + 1;
    const int ks   = lane & 7;        // k-slice within extra-row group
    const int eg   = lane >> 3;       // extra-row group 0..7
    const int erow = 128 + eg;        // extra row 128..135

    // ---- main-row weights: 2 x 68 h2 = 136 VGPR (f16, R6-validated path) ----
    h2 w0[68], w1[68];
#pragma unroll
    for (int p = 0; p < 68; ++p) {
        w0[p] = h2{(_Float16)W_hh[r0 * HID + 2 * p], (_Float16)W_hh[r0 * HID + 2 * p + 1]};
        w1[p] = h2{(_Float16)W_hh[r1 * HID + 2 * p], (_Float16)W_hh[r1 * HID + 2 * p + 1]};
    }
    // ---- extra-row slice weights: 12 h2 ----
    // slices: j<4 -> pair 4ks+j ; j<8 -> pair 32+4ks+(j-4) ; j>=8 -> pair 64+4(ks&1)+(j-8)
    // pairs 64..67 counted once (ks==0); ks==1 reads zero-pad; ks>=2 weights forced 0
    h2 we[12];
#pragma unroll
    for (int j = 0; j < 12; ++j) {
        const int p = (j < 4) ? (4 * ks + j)
                    : (j < 8) ? (32 + 4 * ks + (j - 4))
                              : (64 + 4 * (ks & 1) + (j - 8));
        const int k = 2 * p;
        const bool ok = (j < 8) || (ks < 2);
        const float v0 = (ok && k     < HID) ? W_hh[erow * HID + k]     : 0.0f;
        const float v1 = (ok && k + 1 < HID) ? W_hh[erow * HID + k + 1] : 0.0f;
        we[j] = h2{(_Float16)v0, (_Float16)v1};
    }
    const float wi00 = W_ih[r0 * 2], wi01 = W_ih[r0 * 2 + 1];
    const float wi10 = W_ih[r1 * 2], wi11 = W_ih[r1 * 2 + 1];
    const float wie0 = W_ih[erow * 2], wie1 = W_ih[erow * 2 + 1];
    const float bs0 = b_ih[r0] + b_hh[r0];
    const float bs1 = b_ih[r1] + b_hh[r1];
    const float bse = b_ih[erow] + b_hh[erow];

    // ---- zero hS (single wave, in-order DS pipe) ----
    ((unsigned int*)hS)[lane] = 0u;                       // bytes 0..255
    if (lane < 8) ((unsigned int*)hS)[64 + lane] = 0u;    // bytes 256..287
    __syncthreads();   // once, outside the loop

    const float2* xg = (const float2*)(x + (size_t)b * (TSTEPS * 2));
    float2 xc = xg[0];

    for (int t = 0; t < TSTEPS; ++t) {
        // ---- ALL reads first (program order => in-order DS sees old h) ----
        uint4 hc[17];
#pragma unroll
        for (int i = 0; i < 17; ++i) hc[i] = ((const uint4*)hS)[i];  // broadcast
        uint4 e0 = *(const uint4*)((const char*)hS + 16 * ks);
        uint4 e1 = *(const uint4*)((const char*)hS + 128 + 16 * ks);
        uint4 e2 = *(const uint4*)((const char*)hS + 256 + 16 * (ks & 1));
        const float2 xn = xg[(t + 1) & (TSTEPS - 1)];   // hidden under the step

        // ---- main rows: 136 fdot2, 2 accums per row (static indices) ----
        float a0[2] = {0.f, 0.f}, a1[2] = {0.f, 0.f};
#pragma unroll
        for (int i = 0; i < 17; ++i) {
            const int m = i & 1;
            h2 q0 = bc_h2(hc[i].x), q1 = bc_h2(hc[i].y);
            h2 q2 = bc_h2(hc[i].z), q3 = bc_h2(hc[i].w);
            a0[m] = __builtin_amdgcn_fdot2(q0, w0[4 * i + 0], a0[m], false);
            a1[m] = __builtin_amdgcn_fdot2(q0, w1[4 * i + 0], a1[m], false);
            a0[m] = __builtin_amdgcn_fdot2(q1, w0[4 * i + 1], a0[m], false);
            a1[m] = __builtin_amdgcn_fdot2(q1, w1[4 * i + 1], a1[m], false);
            a0[m] = __builtin_amdgcn_fdot2(q2, w0[4 * i + 2], a0[m], false);
            a1[m] = __builtin_amdgcn_fdot2(q2, w1[4 * i + 2], a1[m], false);
            a0[m] = __builtin_amdgcn_fdot2(q3, w0[4 * i + 3], a0[m], false);
            a1[m] = __builtin_amdgcn_fdot2(q3, w1[4 * i + 3], a1[m], false);
        }

        // ---- extra row (k-split over 8 lanes): 12 fdot2 + reduce8 ----
        float ae = 0.f;
        ae = __builtin_amdgcn_fdot2(bc_h2(e0.x), we[0],  ae, false);
        ae = __builtin_amdgcn_fdot2(bc_h2(e0.y), we[1],  ae, false);
        ae = __builtin_amdgcn_fdot2(bc_h2(e0.z), we[2],  ae, false);
        ae = __builtin_amdgcn_fdot2(bc_h2(e0.w), we[3],  ae, false);
        ae = __builtin_amdgcn_fdot2(bc_h2(e1.x), we[4],  ae, false);
        ae = __builtin_amdgcn_fdot2(bc_h2(e1.y), we[5],  ae, false);
        ae = __builtin_amdgcn_fdot2(bc_h2(e1.z), we[6],  ae, false);
        ae = __builtin_amdgcn_fdot2(bc_h2(e1.w), we[7],  ae, false);
        ae = __builtin_amdgcn_fdot2(bc_h2(e2.x), we[8],  ae, false);
        ae = __builtin_amdgcn_fdot2(bc_h2(e2.y), we[9],  ae, false);
        ae = __builtin_amdgcn_fdot2(bc_h2(e2.z), we[10], ae, false);
        ae = __builtin_amdgcn_fdot2(bc_h2(e2.w), we[11], ae, false);
        ae = reduce8(ae);

        const float z0 = a0[0] + a0[1] + fmaf(xc.x, wi00, fmaf(xc.y, wi01, bs0));
        const float z1 = a1[0] + a1[1] + fmaf(xc.x, wi10, fmaf(xc.y, wi11, bs1));
        const float ze = ae + fmaf(xc.x, wie0, fmaf(xc.y, wie1, bse));

        h2 hw;
        hw.x = (_Float16)fast_tanh(z0);
        hw.y = (_Float16)fast_tanh(z1);
        ((h2*)hS)[lane] = hw;                       // rows 2l,2l+1 (b32 write)
        const _Float16 the = (_Float16)fast_tanh(ze);
        if (ks == 0) hS[128 + eg] = the;            // extra rows 128..135

        xc = xn;
    }

    // ---- final head: out[b][o] = h . W_fc[o,:] + b_fc[o] ----
#pragma unroll
    for (int pass = 0; pass < 2; ++pass) {
        const int o = lane + 64 * pass;
        if (o < ODIM) {
            float s = b_fc[o];
#pragma unroll 8
            for (int k = 0; k < HID; ++k)
                s = fmaf((float)hS[k], W_fc[o * HID + k], s);
            out[b * ODIM + o] = s;
        }
    }
}

extern "C" void kernel_launch(void* const* d_in, const int* in_sizes, int n_in,
                              void* d_out, int out_size, void* d_ws, size_t ws_size,
                              hipStream_t stream) {
    const float* x    = (const float*)d_in[0];
    const float* W_ih = (const float*)d_in[1];
    const float* W_hh = (const float*)d_in[2];
    const float* b_ih = (const float*)d_in[3];
    const float* b_hh = (const float*)d_in[4];
    const float* W_fc = (const float*)d_in[5];
    const float* b_fc = (const float*)d_in[6];
    float* out = (float*)d_out;

    rnn_1w_dot2<<<BATCH, THREADS, 0, stream>>>(x, W_ih, W_hh, b_ih, b_hh,
                                               W_fc, b_fc, out);
}

// Round 12
// 1113.882 us; speedup vs baseline: 1.7387x; 1.7387x over previous
//
#include <hip/hip_runtime.h>

#define BATCH 256
#define TSTEPS 4096
#define HID 136
#define HPADH 144     // h padded to 144 f16 (288 B); f16 slots 136..143 stay 0
#define ODIM 68
#define THREADS 256   // 4 waves, exactly 1 per SIMD

typedef _Float16 h2 __attribute__((ext_vector_type(2)));

__device__ __forceinline__ float fast_tanh(float z) {
    float az = fabsf(z);
    float e = __expf(-2.0f * az);
    float r = (1.0f - e) * __builtin_amdgcn_rcpf(1.0f + e);
    return copysignf(r, z);
}

template <int CTRL>
__device__ __forceinline__ float dpp_add(float x) {
    int y = __builtin_amdgcn_update_dpp(0, __float_as_int(x), CTRL, 0xF, 0xF, false);
    return x + __int_as_float(y);
}
// butterfly over 8 consecutive lanes: all 8 end with the full sum
__device__ __forceinline__ float reduce8(float x) {
    x = dpp_add<0xB1>(x);    // quad_perm xor1
    x = dpp_add<0x4E>(x);    // quad_perm xor2
    x = dpp_add<0x141>(x);   // row_half_mirror
    return x;
}

__device__ __forceinline__ h2 bc_h2(unsigned int u) {
    union { unsigned int u; h2 h; } c; c.u = u; return c.h;
}

// One step: 3 DS reads (2xb128 + b32), 45 fdot2 (5 rows x 9 pairs),
// 5 reduce8, select, 1 tanh, 1 predicated b16 write. XV is a register float2.
#define RNN_STEP(HR, HW, XV)                                                   \
    {                                                                          \
        uint4 u0 = *(const uint4*)((HR) + 16 * ks);                            \
        uint4 u1 = *(const uint4*)((HR) + 16 * ks + 8);                        \
        unsigned int ut = *(const unsigned int*)((HR) + 128 + 2 * ks);         \
        h2 hq[9];                                                              \
        hq[0] = bc_h2(u0.x); hq[1] = bc_h2(u0.y);                              \
        hq[2] = bc_h2(u0.z); hq[3] = bc_h2(u0.w);                              \
        hq[4] = bc_h2(u1.x); hq[5] = bc_h2(u1.y);                              \
        hq[6] = bc_h2(u1.z); hq[7] = bc_h2(u1.w);                              \
        hq[8] = bc_h2(ut);                                                     \
        float a0 = 0.f, a1 = 0.f, a2 = 0.f, a3 = 0.f, a4 = 0.f;                \
        _Pragma("unroll")                                                      \
        for (int q = 0; q < 9; ++q) {                                          \
            a0 = __builtin_amdgcn_fdot2(hq[q], wq[0][q], a0, false);           \
            a1 = __builtin_amdgcn_fdot2(hq[q], wq[1][q], a1, false);           \
            a2 = __builtin_amdgcn_fdot2(hq[q], wq[2][q], a2, false);           \
            a3 = __builtin_amdgcn_fdot2(hq[q], wq[3][q], a3, false);           \
            a4 = __builtin_amdgcn_fdot2(hq[q], wq[4][q], a4, false);           \
        }                                                                      \
        a0 = reduce8(a0);                                                      \
        a1 = reduce8(a1);                                                      \
        a2 = reduce8(a2);                                                      \
        a3 = reduce8(a3);                                                      \
        a4 = reduce8(a4);                                                      \
        float s = a0;                                                          \
        s = (ks == 1) ? a1 : s;                                                \
        s = (ks == 2) ? a2 : s;                                                \
        s = (ks == 3) ? a3 : s;                                                \
        s = (ks == 4) ? a4 : s;                                                \
        float z = fmaf((XV).x, wih0, fmaf((XV).y, wih1, bias)) + s;            \
        float th = fast_tanh(z);                                               \
        if (ks < 4 || (ks == 4 && grp < 2)) (HW)[zrow] = (_Float16)th;         \
    }

__global__ __launch_bounds__(THREADS)
void rnn_fused_kernel(const float* __restrict__ x,
                      const float* __restrict__ W_ih,
                      const float* __restrict__ W_hh,
                      const float* __restrict__ b_ih,
                      const float* __restrict__ b_hh,
                      const float* __restrict__ W_fc,
                      const float* __restrict__ b_fc,
                      float* __restrict__ out)
{
    __shared__ __align__(16) _Float16 hA[HPADH];
    __shared__ __align__(16) _Float16 hB[HPADH];

    const int b   = blockIdx.x;
    const int tid = threadIdx.x;
    const int wv  = tid >> 6;       // wave 0..3
    const int grp = (tid >> 3) & 7; // group index within wave 0..7
    const int g   = tid >> 3;       // global group 0..31 (main rows 4g..4g+3)
    const int ks  = tid & 7;        // k-lane within group

    // extra row: 128 + 2*wv + (g&1)   (128..135; 4 groups redundant each)
    const int erow = 128 + 2 * wv + (g & 1);

    // ---- persistent W_hh f16 pairs: 5 rows x 9 h2 = 45 VGPR ----
    // k map: q<8 -> k = 16*ks + 2q ; q==8 -> k = 128 + 2*ks
    h2 wq[5][9];
#pragma unroll
    for (int j = 0; j < 5; ++j) {
        const int row = (j < 4) ? (4 * g + j) : erow;
#pragma unroll
        for (int q = 0; q < 9; ++q) {
            const int k = (q < 8) ? (16 * ks + 2 * q) : (128 + 2 * ks);
            const float v0 = (k     < HID) ? W_hh[row * HID + k]     : 0.0f;
            const float v1 = (k + 1 < HID) ? W_hh[row * HID + k + 1] : 0.0f;
            wq[j][q] = h2{(_Float16)v0, (_Float16)v1};
        }
    }
    // lane's finished row: ks 0..3 -> main, ks==4 -> extra, 5..7 dummy
    const int zrow = (ks < 4) ? (4 * g + ks) : (ks == 4) ? erow : (4 * g);
    const float wih0 = W_ih[zrow * 2 + 0];
    const float wih1 = W_ih[zrow * 2 + 1];
    const float bias = b_ih[zrow] + b_hh[zrow];

    // ---- zero h buffers (padding stays zero) ----
    if (tid < HPADH) { hA[tid] = (_Float16)0.f; hB[tid] = (_Float16)0.f; }
    __syncthreads();

    // ---- x streamed from global, prefetched 2 steps ahead (register) ----
    const float2* xg = (const float2*)(x + (size_t)b * (TSTEPS * 2));
    float2 xc0 = xg[0];
    float2 xc1 = xg[1];

    for (int t = 0; t < TSTEPS; t += 2) {
        // issue prefetch for t+2 / t+3 early; ~2 full steps of latency cover
        const int tn = (t + 2) & (TSTEPS - 1);
        float2 xn0 = xg[tn];
        float2 xn1 = xg[tn + 1];

        RNN_STEP(hA, hB, xc0);
        __syncthreads();
        RNN_STEP(hB, hA, xc1);
        __syncthreads();

        xc0 = xn0;
        xc1 = xn1;
    }
    // TSTEPS even -> final h in hA

    // ---- final head: out[b][o] = h . W_fc[o,:] + b_fc[o] ----
    if (tid < ODIM) {
        const int o = tid;
        float s = b_fc[o];
#pragma unroll 8
        for (int k = 0; k < HID; ++k)
            s = fmaf((float)hA[k], W_fc[o * HID + k], s);
        out[b * ODIM + o] = s;
    }
}

extern "C" void kernel_launch(void* const* d_in, const int* in_sizes, int n_in,
                              void* d_out, int out_size, void* d_ws, size_t ws_size,
                              hipStream_t stream) {
    const float* x    = (const float*)d_in[0];
    const float* W_ih = (const float*)d_in[1];
    const float* W_hh = (const float*)d_in[2];
    const float* b_ih = (const float*)d_in[3];
    const float* b_hh = (const float*)d_in[4];
    const float* W_fc = (const float*)d_in[5];
    const float* b_fc = (const float*)d_in[6];
    float* out = (float*)d_out;

    rnn_fused_kernel<<<BATCH, THREADS, 0, stream>>>(x, W_ih, W_hh, b_ih, b_hh,
                                                    W_fc, b_fc, out);
}